// Round 11
// baseline (3265.788 us; speedup 1.0000x reference)
//
#include <hip/hip_runtime.h>
#include <stdint.h>

#define Tn 512
#define Hn 512
#define Vn 32000
#define KIN 1024
#define G4 2048
#define NBLK 256
#define PHASES 513
#define PSTR 40           // padded LDS row stride (shorts) for proj_gemm
#define XSTR 1032         // padded LDS row stride (shorts) for scan tiles
#define SLOT_STRIDE 2048  // barrier arrival-slot spacing (bytes)

typedef __attribute__((ext_vector_type(8))) short short8;
typedef __attribute__((ext_vector_type(4))) float f32x4;
typedef __attribute__((ext_vector_type(4))) int i32x4;
typedef __attribute__((ext_vector_type(4))) unsigned u32x4;

__device__ __forceinline__ unsigned short f2bf(float v) {
  unsigned int x = __float_as_uint(v);
  return (unsigned short)((x + 0x7fffu + ((x >> 16) & 1u)) >> 16);  // RNE
}
__device__ __forceinline__ float bf2f(unsigned short u) {
  return __uint_as_float(((unsigned int)u) << 16);
}
// relaxed agent-scope (sc1): served at coherence point, bypass non-coherent L2.
// NO fences anywhere (round-2 lesson: per-thread __threadfence = wbL2 storm).
__device__ __forceinline__ unsigned pollld(const unsigned* p) {
  return __hip_atomic_load(p, __ATOMIC_RELAXED, __HIP_MEMORY_SCOPE_AGENT);
}
__device__ __forceinline__ void flagst(unsigned* p, unsigned v) {
  __hip_atomic_store(p, v, __ATOMIC_RELAXED, __HIP_MEMORY_SCOPE_AGENT);
}

// batched sc1 dwordx4 loads under ONE vmcnt (certified-fresh by the barrier,
// so no polling/retry; one coherence round trip per phase).
__device__ __forceinline__ void ld4x4_sc1(const unsigned* p0, const unsigned* p1,
                                          const unsigned* p2, const unsigned* p3,
                                          u32x4& a, u32x4& b, u32x4& c, u32x4& d) {
  asm volatile(
      "global_load_dwordx4 %0, %4, off sc1\n\t"
      "global_load_dwordx4 %1, %5, off sc1\n\t"
      "global_load_dwordx4 %2, %6, off sc1\n\t"
      "global_load_dwordx4 %3, %7, off sc1\n\t"
      "s_waitcnt vmcnt(0)"
      : "=&v"(a), "=&v"(b), "=&v"(c), "=&v"(d)
      : "v"(p0), "v"(p1), "v"(p2), "v"(p3)
      : "memory");
}
__device__ __forceinline__ void ld8x4_sc1(
    const unsigned* p0, const unsigned* p1, const unsigned* p2, const unsigned* p3,
    const unsigned* p4, const unsigned* p5, const unsigned* p6, const unsigned* p7,
    u32x4& a, u32x4& b, u32x4& c, u32x4& d,
    u32x4& e, u32x4& f, u32x4& g, u32x4& h) {
  asm volatile(
      "global_load_dwordx4 %0, %8, off sc1\n\t"
      "global_load_dwordx4 %1, %9, off sc1\n\t"
      "global_load_dwordx4 %2, %10, off sc1\n\t"
      "global_load_dwordx4 %3, %11, off sc1\n\t"
      "global_load_dwordx4 %4, %12, off sc1\n\t"
      "global_load_dwordx4 %5, %13, off sc1\n\t"
      "global_load_dwordx4 %6, %14, off sc1\n\t"
      "global_load_dwordx4 %7, %15, off sc1\n\t"
      "s_waitcnt vmcnt(0)"
      : "=&v"(a), "=&v"(b), "=&v"(c), "=&v"(d),
        "=&v"(e), "=&v"(f), "=&v"(g), "=&v"(h)
      : "v"(p0), "v"(p1), "v"(p2), "v"(p3),
        "v"(p4), "v"(p5), "v"(p6), "v"(p7)
      : "memory");
}

// 8 packed (hi16|lo16) u32 -> 16B hi shorts + 16B lo shorts (one group)
__device__ __forceinline__ void unpack8(const u32x4& a, const u32x4& b,
                                        unsigned short* XhDst, unsigned short* XlDst) {
  unsigned hw[4], lw[4];
  hw[0] = (a[0] >> 16) | (a[1] & 0xffff0000u);
  lw[0] = (a[0] & 0xffffu) | (a[1] << 16);
  hw[1] = (a[2] >> 16) | (a[3] & 0xffff0000u);
  lw[1] = (a[2] & 0xffffu) | (a[3] << 16);
  hw[2] = (b[0] >> 16) | (b[1] & 0xffff0000u);
  lw[2] = (b[0] & 0xffffu) | (b[1] << 16);
  hw[3] = (b[2] >> 16) | (b[3] & 0xffff0000u);
  lw[3] = (b[2] & 0xffffu) | (b[3] << 16);
  *(u32x4*)XhDst = *(const u32x4*)hw;
  *(u32x4*)XlDst = *(const u32x4*)lw;
}

// 8 f32 -> 16B hi shorts + 16B lo shorts (one group)
__device__ __forceinline__ void cvt8(const f32x4& v0, const f32x4& v1,
                                     unsigned short* XhDst, unsigned short* XlDst) {
  unsigned short h8[8], l8[8];
#pragma unroll
  for (int i = 0; i < 4; ++i) {
    h8[i]     = f2bf(v0[i]); l8[i]     = f2bf(v0[i] - bf2f(h8[i]));
    h8[4 + i] = f2bf(v1[i]); l8[4 + i] = f2bf(v1[i] - bf2f(h8[4 + i]));
  }
  *(u32x4*)XhDst = *(const u32x4*)h8;
  *(u32x4*)XlDst = *(const u32x4*)l8;
}

// ---------------- Wout f32 -> transposed bf16 hi/lo [V][H] ----------------
__global__ __launch_bounds__(256) void wout_convert(const float* __restrict__ Wout,
                                                    unsigned short* __restrict__ BhT,
                                                    unsigned short* __restrict__ BlT) {
  __shared__ float ts[64][65];
  const int n0 = blockIdx.x * 64;
  const int k0 = blockIdx.y * 64;
  const int tid = threadIdx.x;
  {
    const int c = tid & 63, rq = tid >> 6;
#pragma unroll
    for (int i = 0; i < 16; ++i) {
      const int k = rq * 16 + i;
      ts[k][c] = Wout[(size_t)(k0 + k) * Vn + (n0 + c)];
    }
  }
  __syncthreads();
  {
    const int nl = tid >> 2;
    const int ks = (tid & 3) * 16;
    unsigned short hb[16], lb[16];
#pragma unroll
    for (int i = 0; i < 16; ++i) {
      const float v = ts[ks + i][nl];
      const unsigned short h = f2bf(v);
      hb[i] = h;
      lb[i] = f2bf(v - bf2f(h));
    }
    const size_t base = (size_t)(n0 + nl) * Hn + (k0 + ks);
    *(i32x4*)&BhT[base]     = *(const i32x4*)&hb[0];
    *(i32x4*)&BhT[base + 8] = *(const i32x4*)&hb[8];
    *(i32x4*)&BlT[base]     = *(const i32x4*)&lb[0];
    *(i32x4*)&BlT[base + 8] = *(const i32x4*)&lb[8];
  }
}

// ---------------- persistent fused 2-layer LSTM scan (MFMA core) -----------
// Round-10 proven skeleton, 3-sync tail: 256 blocks x 512 threads, 1 block/CU.
// blocks 0..127: layer 0 (t = ph), 128..255: layer 1 (t = ph-1). Per phase:
// certified h exchange (2-slot double buffer, packed u32 hi|lo) + flat device
// barrier. New: reduce fused into wave0 act (same FP order), wave-local vmcnt
// drain before the arrival flag (other waves prestage/poll during wave0's RT).
__global__ __launch_bounds__(512) void lstm_scan(
    const int* __restrict__ tokens, const float* __restrict__ embed,
    const float* __restrict__ Wg, const float* __restrict__ bg,
    unsigned* __restrict__ hex1, unsigned* __restrict__ hex2,  // [2][16][512] u32
    unsigned short* __restrict__ Ah, unsigned short* __restrict__ Al,
    unsigned* __restrict__ arr) {

  extern __shared__ char smembytes[];
  unsigned short* Wh  = (unsigned short*)smembytes;  // [16][XSTR] bf16 hi
  unsigned short* Wlo = Wh + 16 * XSTR;              // [16][XSTR] bf16 lo
  unsigned short* Xh  = Wlo + 16 * XSTR;             // [16][XSTR] xh hi
  unsigned short* Xl  = Xh + 16 * XSTR;              // [16][XSTR] xh lo
  float* red = (float*)(Xl + 16 * XSTR);             // [8][272]

  const int tid = threadIdx.x;
  const int bid = blockIdx.x;
  const int layer = bid >> 7;
  const int u0 = (bid & 127) * 4;

  // one-time: W slice (cols = gate*512 + u0 + j) -> bf16 hi/lo in LDS
  for (int idx = tid; idx < 16 * KIN; idx += 512) {
    const int k = idx >> 4;
    const int c = idx & 15;
    const int col = ((c >> 2) << 9) + u0 + (c & 3);
    const float wv = Wg[(size_t)layer * KIN * G4 + (size_t)k * G4 + col];
    const unsigned short h = f2bf(wv);
    Wh[c * XSTR + k] = h;
    Wlo[c * XSTR + k] = f2bf(wv - bf2f(h));
  }

  float bb0 = 0.f, bb1 = 0.f, bb2 = 0.f, bb3 = 0.f, c_state = 0.f;
  if (tid < 64) {
    const int j = tid & 3;
    bb0 = bg[layer * G4 + 0 * 512 + u0 + j];
    bb1 = bg[layer * G4 + 1 * 512 + u0 + j];
    bb2 = bg[layer * G4 + 2 * 512 + u0 + j];
    bb3 = bg[layer * G4 + 3 * 512 + u0 + j];
  }

  const int lane = tid & 63;
  const int w = tid >> 6;          // wave 0..7: K-slice [w*128, w*128+128)
  const int m = lane & 15;         // MFMA fragment row selector
  const int g8 = (lane >> 4) * 8;  // k-octet within the 32-k MFMA window

  // staging groups (conflict-free: consecutive lanes -> consecutive 16B writes)
  const int gA = tid, gB = tid + 512;
  const int rowA = gA >> 6, slotA = gA & 63;
  const int rowB = gB >> 6, slotB = gB & 63;
  const int offA = rowA * XSTR + slotA * 8;
  const int offB = rowB * XSTR + slotB * 8;

  unsigned* bar_my = (unsigned*)((char*)arr + (size_t)bid * SLOT_STRIDE);
  const unsigned* bar_poll =
      (const unsigned*)((const char*)arr + (size_t)(tid & 255) * SLOT_STRIDE);

  __syncthreads();

  // hoist this wave's W fragments into registers (halves per-phase LDS reads)
  short8 wh_r[4], wl_r[4];
#pragma unroll
  for (int it = 0; it < 4; ++it) {
    const int kb = w * 128 + it * 32 + g8;
    wh_r[it] = *(const short8*)&Wh[m * XSTR + kb];
    wl_r[it] = *(const short8*)&Wlo[m * XSTR + kb];
  }

  // prologue: L0 stages x(t=0) from embed
  if (layer == 0) {
    const int tokA = tokens[rowA * Tn + 0];
    const int tokB = tokens[rowB * Tn + 0];
    const float* sA = embed + (size_t)tokA * Hn + slotA * 8;
    const float* sB = embed + (size_t)tokB * Hn + slotB * 8;
    cvt8(*(const f32x4*)sA, *(const f32x4*)(sA + 4), &Xh[offA], &Xl[offA]);
    cvt8(*(const f32x4*)sB, *(const f32x4*)(sB + 4), &Xh[offB], &Xl[offB]);
  }

  for (int ph = 0; ph < PHASES; ++ph) {
    const unsigned target = (unsigned)(ph + 1);
    const bool act = (layer == 0) ? (ph < Tn) : (ph >= 1);

    // --- stage h (and L1's x) from coherence point; certified by the barrier.
    // ph==0 (L0) / ph==1 (L1) read the zero-initialized opposite slot = h[-1]=0.
    if (act) {
      if (layer == 0) {
        const unsigned* hb = hex1 + ((ph - 1) & 1) * 8192;
        u32x4 a, b, c, d;
        ld4x4_sc1(hb + gA * 8, hb + gA * 8 + 4, hb + gB * 8, hb + gB * 8 + 4,
                  a, b, c, d);
        unpack8(a, b, &Xh[offA + 512], &Xl[offA + 512]);
        unpack8(c, d, &Xh[offB + 512], &Xl[offB + 512]);
      } else {
        const unsigned* xb = hex1 + ((ph - 1) & 1) * 8192;  // x = h1[ph-1]
        const unsigned* hb = hex2 + (ph & 1) * 8192;        // h = h2[ph-2]
        u32x4 x0, x1, x2, x3, h0, h1v, h2v, h3;
        ld8x4_sc1(xb + gA * 8, xb + gA * 8 + 4, xb + gB * 8, xb + gB * 8 + 4,
                  hb + gA * 8, hb + gA * 8 + 4, hb + gB * 8, hb + gB * 8 + 4,
                  x0, x1, x2, x3, h0, h1v, h2v, h3);
        unpack8(x0, x1, &Xh[offA], &Xl[offA]);
        unpack8(x2, x3, &Xh[offB], &Xl[offB]);
        unpack8(h0, h1v, &Xh[offA + 512], &Xl[offA + 512]);
        unpack8(h2v, h3, &Xh[offB + 512], &Xl[offB + 512]);
      }
    }
    __syncthreads();  // S1: LDS tiles ready

    // --- MFMA dot: 12 mfma per wave, W operands from registers ---
    if (act) {
      f32x4 acc = {0.f, 0.f, 0.f, 0.f};
#pragma unroll
      for (int it = 0; it < 4; ++it) {
        const int kb = w * 128 + it * 32 + g8;
        const short8 ahf = *(const short8*)&Xh[m * XSTR + kb];
        const short8 alf = *(const short8*)&Xl[m * XSTR + kb];
        acc = __builtin_amdgcn_mfma_f32_16x16x32_bf16(ahf, wh_r[it], acc, 0, 0, 0);
        acc = __builtin_amdgcn_mfma_f32_16x16x32_bf16(ahf, wl_r[it], acc, 0, 0, 0);
        acc = __builtin_amdgcn_mfma_f32_16x16x32_bf16(alf, wh_r[it], acc, 0, 0, 0);
      }
      // C/D layout: col = lane&15, row = (lane>>4)*4 + reg (m89-verified)
      const int r0 = (lane >> 4) * 4;
#pragma unroll
      for (int r = 0; r < 4; ++r)
        red[w * 272 + (r0 + r) * 17 + m] = acc[r];
    }
    __syncthreads();  // S2: all red partials visible

    // --- wave0: fused reduce + activations + packed h publish ---
    if (act && tid < 64) {
      const int b = tid >> 2, j = tid & 3;
      float g4[4];
#pragma unroll
      for (int g = 0; g < 4; ++g) {
        const int c = g * 4 + j;
        float s = 0.f;
#pragma unroll
        for (int ww = 0; ww < 8; ++ww) s += red[ww * 272 + b * 17 + c];
        g4[g] = s;
      }
      const float gi = g4[0] + bb0;
      const float gf = g4[1] + bb1;
      const float gg = g4[2] + bb2;
      const float go = g4[3] + bb3;
      const float si = 1.f / (1.f + __expf(-gi));
      const float sf = 1.f / (1.f + __expf(-gf));
      const float e2g = __expf(2.f * gg);
      const float tg = 1.f - 2.f / (e2g + 1.f);
      const float so = 1.f / (1.f + __expf(-go));
      const float cn = sf * c_state + si * tg;
      c_state = cn;
      const float e2c = __expf(2.f * cn);
      const float hn = so * (1.f - 2.f / (e2c + 1.f));
      const unsigned short hh = f2bf(hn);
      const unsigned short hl = f2bf(hn - bf2f(hh));
      const unsigned pk = ((unsigned)hh << 16) | (unsigned)hl;
      unsigned* hdst = (layer == 0)
          ? hex1 + (ph & 1) * 8192 + b * 512 + (u0 + j)
          : hex2 + ((ph - 1) & 1) * 8192 + b * 512 + (u0 + j);
      flagst(hdst, pk);  // sc1 -> coherence point
      if (layer == 1) {
        const size_t r = (size_t)(ph - 1) * 16 + b;
        Ah[r * Hn + u0 + j] = hh;
        Al[r * Hn + u0 + j] = hl;
      }
    }
    // wave-local drain of wave0's publish stores, then arrival flag (only
    // wave0 stores h, so a block-wide drain-sync is unnecessary).
    if (tid < 64) {
      asm volatile("s_waitcnt vmcnt(0)" ::: "memory");
      if (tid == 0) flagst(bar_my, target);
    }

    // --- overlap the wait: L0 pre-stages embed x for the next step
    //     (writes only the x-half, disjoint from everything read this phase) ---
    if (layer == 0 && (ph + 1) < Tn) {
      const int t1 = ph + 1;
      const int tokA = tokens[rowA * Tn + t1];
      const int tokB = tokens[rowB * Tn + t1];
      const float* sA = embed + (size_t)tokA * Hn + slotA * 8;
      const float* sB = embed + (size_t)tokB * Hn + slotB * 8;
      cvt8(*(const f32x4*)sA, *(const f32x4*)(sA + 4), &Xh[offA], &Xl[offA]);
      cvt8(*(const f32x4*)sB, *(const f32x4*)(sB + 4), &Xh[offB], &Xl[offB]);
    }

    // --- flat certify barrier ---
    if (tid < 256) {
      while (pollld(bar_poll) < target) __builtin_amdgcn_s_sleep(2);
    }
    __syncthreads();  // S3: end of phase
  }
}

// ---------------- projection GEMM: out[b][t][v] = H2 @ Wout + bout ----------
// XCD-banded grid: each XCD owns an 8-m-tile A band (2.1 MB, L2-resident);
// 8 consecutive blocks on an XCD share one B panel (262 KB, L2-resident).
__global__ __launch_bounds__(256) void proj_gemm(
    const unsigned short* __restrict__ Ah_, const unsigned short* __restrict__ Al_,
    const unsigned short* __restrict__ Bh_, const unsigned short* __restrict__ Bl_,
    const float* __restrict__ bout, float* __restrict__ out) {
  __shared__ unsigned short sAh[128 * PSTR], sAl[128 * PSTR], sBh[128 * PSTR], sBl[128 * PSTR];
  const int tid = threadIdx.x;
  const int id = blockIdx.x;
  // bijective remap: xcd = id&7 gets m-tiles [8*xcd, 8*xcd+8), n sweeps slowest
  const int mt = (id & 7) * 8 + ((id >> 3) & 7);   // 0..63
  const int m0 = mt * 128;
  const int n0 = (id >> 6) * 128;                  // 0..249 tiles
  const int lane = tid & 63, w = tid >> 6;
  const int wm = (w & 1) * 64, wn = (w >> 1) * 64;

  f32x4 acc[4][4];
#pragma unroll
  for (int i = 0; i < 4; ++i)
#pragma unroll
    for (int j = 0; j < 4; ++j) acc[i][j] = (f32x4){0.f, 0.f, 0.f, 0.f};

  for (int kt = 0; kt < 16; ++kt) {
    const int k0 = kt * 32;
    __syncthreads();
#pragma unroll
    for (int i = 0; i < 8; ++i) {
      const int chunk = ((i & 1) << 8) + tid;
      const int mrow = chunk >> 2;
      const int kc = chunk & 3;
      const int tsel = i >> 1;
      const unsigned short* gsrc =
          (tsel == 0) ? Ah_ + (size_t)(m0 + mrow) * Hn + k0 + kc * 8 :
          (tsel == 1) ? Al_ + (size_t)(m0 + mrow) * Hn + k0 + kc * 8 :
          (tsel == 2) ? Bh_ + (size_t)(n0 + mrow) * Hn + k0 + kc * 8 :
                        Bl_ + (size_t)(n0 + mrow) * Hn + k0 + kc * 8;
      unsigned short* ldst = (tsel == 0) ? sAh : (tsel == 1) ? sAl : (tsel == 2) ? sBh : sBl;
      *(i32x4*)&ldst[mrow * PSTR + kc * 8] = *(const i32x4*)gsrc;
    }
    __syncthreads();

    short8 fah[4], fal[4], fbh[4], fbl[4];
    const int rlo = lane & 15, kg = (lane >> 4) * 8;
#pragma unroll
    for (int f = 0; f < 4; ++f) {
      fah[f] = *(const short8*)&sAh[(wm + f * 16 + rlo) * PSTR + kg];
      fal[f] = *(const short8*)&sAl[(wm + f * 16 + rlo) * PSTR + kg];
      fbh[f] = *(const short8*)&sBh[(wn + f * 16 + rlo) * PSTR + kg];
      fbl[f] = *(const short8*)&sBl[(wn + f * 16 + rlo) * PSTR + kg];
    }
#pragma unroll
    for (int i = 0; i < 4; ++i)
#pragma unroll
      for (int j = 0; j < 4; ++j) {
        acc[i][j] = __builtin_amdgcn_mfma_f32_16x16x32_bf16(fah[i], fbh[j], acc[i][j], 0, 0, 0);
        acc[i][j] = __builtin_amdgcn_mfma_f32_16x16x32_bf16(fah[i], fbl[j], acc[i][j], 0, 0, 0);
        acc[i][j] = __builtin_amdgcn_mfma_f32_16x16x32_bf16(fal[i], fbh[j], acc[i][j], 0, 0, 0);
      }
  }

#pragma unroll
  for (int j = 0; j < 4; ++j) {
    const int n = n0 + wn + j * 16 + (lane & 15);
    const float bv = bout[n];
#pragma unroll
    for (int i = 0; i < 4; ++i) {
#pragma unroll
      for (int r = 0; r < 4; ++r) {
        const int m = m0 + wm + i * 16 + ((lane >> 4) * 4) + r;
        out[(size_t)(m & 15) * ((size_t)Tn * Vn) + (size_t)(m >> 4) * Vn + n] =
            acc[i][j][r] + bv;
      }
    }
  }
}

extern "C" void kernel_launch(void* const* d_in, const int* in_sizes, int n_in,
                              void* d_out, int out_size, void* d_ws, size_t ws_size,
                              hipStream_t stream) {
  const int*   tokens = (const int*)d_in[0];
  const float* embed  = (const float*)d_in[1];
  const float* W      = (const float*)d_in[2];
  const float* bias   = (const float*)d_in[3];
  const float* Wout   = (const float*)d_in[4];
  const float* bout   = (const float*)d_in[5];
  float* out = (float*)d_out;

  char* ws = (char*)d_ws;
  unsigned* arr  = (unsigned*)ws;                      // 256 * 2048 B barrier slots
  unsigned* hex1 = (unsigned*)(ws + 524288);           // 2 slots * 16*512 u32
  unsigned* hex2 = (unsigned*)(ws + 524288 + 65536);   // 2 slots * 16*512 u32
  unsigned short* Ah  = (unsigned short*)(ws + 655360);
  unsigned short* Al  = Ah + (size_t)8192 * 512;
  unsigned short* BhT = Al + (size_t)8192 * 512;
  unsigned short* BlT = BhT + (size_t)32000 * 512;
  // total ws use: ~83 MB

  // zero barrier slots + packed h exchange buffers (fresh every launch;
  // zeroed hex slots double as h[-1] = 0 for the first phases)
  hipMemsetAsync(d_ws, 0, 655360, stream);

  wout_convert<<<dim3(500, 8), 256, 0, stream>>>(Wout, BhT, BlT);

  const size_t ldsbytes = (size_t)(4 * 16 * XSTR) * 2 + (size_t)(8 * 272) * 4;  // 140800
  (void)hipFuncSetAttribute((const void*)lstm_scan,
                            hipFuncAttributeMaxDynamicSharedMemorySize, (int)ldsbytes);
  lstm_scan<<<NBLK, 512, ldsbytes, stream>>>(tokens, embed, W, bias,
                                             hex1, hex2, Ah, Al, arr);

  proj_gemm<<<16000, 256, 0, stream>>>(Ah, Al, BhT, BlT, bout, out);
}

// Round 12
// 2776.395 us; speedup vs baseline: 1.1763x; 1.1763x over previous
//
#include <hip/hip_runtime.h>
#include <stdint.h>

#define Tn 512
#define Hn 512
#define Vn 32000
#define KIN 1024
#define G4 2048
#define NBLK 256
#define PHASES 513
#define PSTR 40           // padded LDS row stride (shorts) for proj_gemm
#define XSTR 1032         // padded LDS row stride (shorts) for scan tiles
#define SLOT_STRIDE 2048  // barrier arrival-slot spacing (bytes)

typedef __attribute__((ext_vector_type(8))) short short8;
typedef __attribute__((ext_vector_type(4))) float f32x4;
typedef __attribute__((ext_vector_type(4))) int i32x4;
typedef __attribute__((ext_vector_type(4))) unsigned u32x4;

__device__ __forceinline__ unsigned short f2bf(float v) {
  unsigned int x = __float_as_uint(v);
  return (unsigned short)((x + 0x7fffu + ((x >> 16) & 1u)) >> 16);  // RNE
}
__device__ __forceinline__ float bf2f(unsigned short u) {
  return __uint_as_float(((unsigned int)u) << 16);
}
// relaxed agent-scope (sc1): served at coherence point, bypass non-coherent L2.
// NO fences anywhere (round-2 lesson: per-thread __threadfence = wbL2 storm).
__device__ __forceinline__ unsigned pollld(const unsigned* p) {
  return __hip_atomic_load(p, __ATOMIC_RELAXED, __HIP_MEMORY_SCOPE_AGENT);
}
__device__ __forceinline__ void flagst(unsigned* p, unsigned v) {
  __hip_atomic_store(p, v, __ATOMIC_RELAXED, __HIP_MEMORY_SCOPE_AGENT);
}

// batched sc1 dwordx4 loads under ONE vmcnt (certified-fresh by the barrier,
// so no polling/retry; one coherence round trip per phase).
__device__ __forceinline__ void ld4x4_sc1(const unsigned* p0, const unsigned* p1,
                                          const unsigned* p2, const unsigned* p3,
                                          u32x4& a, u32x4& b, u32x4& c, u32x4& d) {
  asm volatile(
      "global_load_dwordx4 %0, %4, off sc1\n\t"
      "global_load_dwordx4 %1, %5, off sc1\n\t"
      "global_load_dwordx4 %2, %6, off sc1\n\t"
      "global_load_dwordx4 %3, %7, off sc1\n\t"
      "s_waitcnt vmcnt(0)"
      : "=&v"(a), "=&v"(b), "=&v"(c), "=&v"(d)
      : "v"(p0), "v"(p1), "v"(p2), "v"(p3)
      : "memory");
}
__device__ __forceinline__ void ld8x4_sc1(
    const unsigned* p0, const unsigned* p1, const unsigned* p2, const unsigned* p3,
    const unsigned* p4, const unsigned* p5, const unsigned* p6, const unsigned* p7,
    u32x4& a, u32x4& b, u32x4& c, u32x4& d,
    u32x4& e, u32x4& f, u32x4& g, u32x4& h) {
  asm volatile(
      "global_load_dwordx4 %0, %8, off sc1\n\t"
      "global_load_dwordx4 %1, %9, off sc1\n\t"
      "global_load_dwordx4 %2, %10, off sc1\n\t"
      "global_load_dwordx4 %3, %11, off sc1\n\t"
      "global_load_dwordx4 %4, %12, off sc1\n\t"
      "global_load_dwordx4 %5, %13, off sc1\n\t"
      "global_load_dwordx4 %6, %14, off sc1\n\t"
      "global_load_dwordx4 %7, %15, off sc1\n\t"
      "s_waitcnt vmcnt(0)"
      : "=&v"(a), "=&v"(b), "=&v"(c), "=&v"(d),
        "=&v"(e), "=&v"(f), "=&v"(g), "=&v"(h)
      : "v"(p0), "v"(p1), "v"(p2), "v"(p3),
        "v"(p4), "v"(p5), "v"(p6), "v"(p7)
      : "memory");
}

// 8 packed (hi16|lo16) u32 -> 16B hi shorts + 16B lo shorts (one group)
__device__ __forceinline__ void unpack8(const u32x4& a, const u32x4& b,
                                        unsigned short* XhDst, unsigned short* XlDst) {
  unsigned hw[4], lw[4];
  hw[0] = (a[0] >> 16) | (a[1] & 0xffff0000u);
  lw[0] = (a[0] & 0xffffu) | (a[1] << 16);
  hw[1] = (a[2] >> 16) | (a[3] & 0xffff0000u);
  lw[1] = (a[2] & 0xffffu) | (a[3] << 16);
  hw[2] = (b[0] >> 16) | (b[1] & 0xffff0000u);
  lw[2] = (b[0] & 0xffffu) | (b[1] << 16);
  hw[3] = (b[2] >> 16) | (b[3] & 0xffff0000u);
  lw[3] = (b[2] & 0xffffu) | (b[3] << 16);
  *(u32x4*)XhDst = *(const u32x4*)hw;
  *(u32x4*)XlDst = *(const u32x4*)lw;
}

// 8 f32 -> 16B hi shorts + 16B lo shorts (one group)
__device__ __forceinline__ void cvt8(const f32x4& v0, const f32x4& v1,
                                     unsigned short* XhDst, unsigned short* XlDst) {
  unsigned short h8[8], l8[8];
#pragma unroll
  for (int i = 0; i < 4; ++i) {
    h8[i]     = f2bf(v0[i]); l8[i]     = f2bf(v0[i] - bf2f(h8[i]));
    h8[4 + i] = f2bf(v1[i]); l8[4 + i] = f2bf(v1[i] - bf2f(h8[4 + i]));
  }
  *(u32x4*)XhDst = *(const u32x4*)h8;
  *(u32x4*)XlDst = *(const u32x4*)l8;
}

// ---------------- Wout f32 -> transposed bf16 hi/lo [V][H] ----------------
__global__ __launch_bounds__(256) void wout_convert(const float* __restrict__ Wout,
                                                    unsigned short* __restrict__ BhT,
                                                    unsigned short* __restrict__ BlT) {
  __shared__ float ts[64][65];
  const int n0 = blockIdx.x * 64;
  const int k0 = blockIdx.y * 64;
  const int tid = threadIdx.x;
  {
    const int c = tid & 63, rq = tid >> 6;
#pragma unroll
    for (int i = 0; i < 16; ++i) {
      const int k = rq * 16 + i;
      ts[k][c] = Wout[(size_t)(k0 + k) * Vn + (n0 + c)];
    }
  }
  __syncthreads();
  {
    const int nl = tid >> 2;
    const int ks = (tid & 3) * 16;
    unsigned short hb[16], lb[16];
#pragma unroll
    for (int i = 0; i < 16; ++i) {
      const float v = ts[ks + i][nl];
      const unsigned short h = f2bf(v);
      hb[i] = h;
      lb[i] = f2bf(v - bf2f(h));
    }
    const size_t base = (size_t)(n0 + nl) * Hn + (k0 + ks);
    *(i32x4*)&BhT[base]     = *(const i32x4*)&hb[0];
    *(i32x4*)&BhT[base + 8] = *(const i32x4*)&hb[8];
    *(i32x4*)&BlT[base]     = *(const i32x4*)&lb[0];
    *(i32x4*)&BlT[base + 8] = *(const i32x4*)&lb[8];
  }
}

// ---------------- persistent fused 2-layer LSTM scan (MFMA core) -----------
// Round-10 proven skeleton (restored verbatim after round-11 regression):
// 256 blocks x 512 threads, 1 block/CU. blocks 0..127: layer 0 (t = ph),
// 128..255: layer 1 (t = ph-1). Per phase: certified h exchange (2-slot
// double buffer, packed u32 hi|lo) + flat device barrier (2KB-strided slots).
// Tail is reduce(256)->gates->act(64)->BLOCK-WIDE drain-sync->flag: the
// block-wide drain keeps pollers off the fabric until publishes are committed
// (round-11 lesson: wave-local drain lets 192 pollers contend with wave0's
// publish stores, +1.07 us/phase).
__global__ __launch_bounds__(512) void lstm_scan(
    const int* __restrict__ tokens, const float* __restrict__ embed,
    const float* __restrict__ Wg, const float* __restrict__ bg,
    unsigned* __restrict__ hex1, unsigned* __restrict__ hex2,  // [2][16][512] u32
    unsigned short* __restrict__ Ah, unsigned short* __restrict__ Al,
    unsigned* __restrict__ arr) {

  extern __shared__ char smembytes[];
  unsigned short* Wh  = (unsigned short*)smembytes;  // [16][XSTR] bf16 hi
  unsigned short* Wlo = Wh + 16 * XSTR;              // [16][XSTR] bf16 lo
  unsigned short* Xh  = Wlo + 16 * XSTR;             // [16][XSTR] xh hi
  unsigned short* Xl  = Xh + 16 * XSTR;              // [16][XSTR] xh lo
  float* red   = (float*)(Xl + 16 * XSTR);           // [8][272]
  float* gates = red + 8 * 272;                      // [256]

  const int tid = threadIdx.x;
  const int bid = blockIdx.x;
  const int layer = bid >> 7;
  const int u0 = (bid & 127) * 4;

  // one-time: W slice (cols = gate*512 + u0 + j) -> bf16 hi/lo in LDS
  for (int idx = tid; idx < 16 * KIN; idx += 512) {
    const int k = idx >> 4;
    const int c = idx & 15;
    const int col = ((c >> 2) << 9) + u0 + (c & 3);
    const float wv = Wg[(size_t)layer * KIN * G4 + (size_t)k * G4 + col];
    const unsigned short h = f2bf(wv);
    Wh[c * XSTR + k] = h;
    Wlo[c * XSTR + k] = f2bf(wv - bf2f(h));
  }

  float bb0 = 0.f, bb1 = 0.f, bb2 = 0.f, bb3 = 0.f, c_state = 0.f;
  if (tid < 64) {
    const int j = tid & 3;
    bb0 = bg[layer * G4 + 0 * 512 + u0 + j];
    bb1 = bg[layer * G4 + 1 * 512 + u0 + j];
    bb2 = bg[layer * G4 + 2 * 512 + u0 + j];
    bb3 = bg[layer * G4 + 3 * 512 + u0 + j];
  }

  const int lane = tid & 63;
  const int w = tid >> 6;          // wave 0..7: K-slice [w*128, w*128+128)
  const int m = lane & 15;         // MFMA fragment row selector
  const int g8 = (lane >> 4) * 8;  // k-octet within the 32-k MFMA window

  // staging groups (conflict-free: consecutive lanes -> consecutive 16B writes)
  const int gA = tid, gB = tid + 512;
  const int rowA = gA >> 6, slotA = gA & 63;
  const int rowB = gB >> 6, slotB = gB & 63;
  const int offA = rowA * XSTR + slotA * 8;
  const int offB = rowB * XSTR + slotB * 8;

  unsigned* bar_my = (unsigned*)((char*)arr + (size_t)bid * SLOT_STRIDE);
  const unsigned* bar_poll =
      (const unsigned*)((const char*)arr + (size_t)(tid & 255) * SLOT_STRIDE);

  __syncthreads();

  // hoist this wave's W fragments into registers (halves per-phase LDS reads)
  short8 wh_r[4], wl_r[4];
#pragma unroll
  for (int it = 0; it < 4; ++it) {
    const int kb = w * 128 + it * 32 + g8;
    wh_r[it] = *(const short8*)&Wh[m * XSTR + kb];
    wl_r[it] = *(const short8*)&Wlo[m * XSTR + kb];
  }

  // prologue: L0 stages x(t=0) from embed
  if (layer == 0) {
    const int tokA = tokens[rowA * Tn + 0];
    const int tokB = tokens[rowB * Tn + 0];
    const float* sA = embed + (size_t)tokA * Hn + slotA * 8;
    const float* sB = embed + (size_t)tokB * Hn + slotB * 8;
    cvt8(*(const f32x4*)sA, *(const f32x4*)(sA + 4), &Xh[offA], &Xl[offA]);
    cvt8(*(const f32x4*)sB, *(const f32x4*)(sB + 4), &Xh[offB], &Xl[offB]);
  }

  for (int ph = 0; ph < PHASES; ++ph) {
    const unsigned target = (unsigned)(ph + 1);
    const bool act = (layer == 0) ? (ph < Tn) : (ph >= 1);

    // --- stage h (and L1's x) from coherence point; certified by the barrier.
    // ph==0 (L0) / ph==1 (L1) read the zero-initialized opposite slot = h[-1]=0.
    if (act) {
      if (layer == 0) {
        const unsigned* hb = hex1 + ((ph - 1) & 1) * 8192;
        u32x4 a, b, c, d;
        ld4x4_sc1(hb + gA * 8, hb + gA * 8 + 4, hb + gB * 8, hb + gB * 8 + 4,
                  a, b, c, d);
        unpack8(a, b, &Xh[offA + 512], &Xl[offA + 512]);
        unpack8(c, d, &Xh[offB + 512], &Xl[offB + 512]);
      } else {
        const unsigned* xb = hex1 + ((ph - 1) & 1) * 8192;  // x = h1[ph-1]
        const unsigned* hb = hex2 + (ph & 1) * 8192;        // h = h2[ph-2]
        u32x4 x0, x1, x2, x3, h0, h1v, h2v, h3;
        ld8x4_sc1(xb + gA * 8, xb + gA * 8 + 4, xb + gB * 8, xb + gB * 8 + 4,
                  hb + gA * 8, hb + gA * 8 + 4, hb + gB * 8, hb + gB * 8 + 4,
                  x0, x1, x2, x3, h0, h1v, h2v, h3);
        unpack8(x0, x1, &Xh[offA], &Xl[offA]);
        unpack8(x2, x3, &Xh[offB], &Xl[offB]);
        unpack8(h0, h1v, &Xh[offA + 512], &Xl[offA + 512]);
        unpack8(h2v, h3, &Xh[offB + 512], &Xl[offB + 512]);
      }
    }
    __syncthreads();

    // --- MFMA dot: 12 mfma per wave, W operands from registers ---
    if (act) {
      f32x4 acc = {0.f, 0.f, 0.f, 0.f};
#pragma unroll
      for (int it = 0; it < 4; ++it) {
        const int kb = w * 128 + it * 32 + g8;
        const short8 ahf = *(const short8*)&Xh[m * XSTR + kb];
        const short8 alf = *(const short8*)&Xl[m * XSTR + kb];
        acc = __builtin_amdgcn_mfma_f32_16x16x32_bf16(ahf, wh_r[it], acc, 0, 0, 0);
        acc = __builtin_amdgcn_mfma_f32_16x16x32_bf16(ahf, wl_r[it], acc, 0, 0, 0);
        acc = __builtin_amdgcn_mfma_f32_16x16x32_bf16(alf, wh_r[it], acc, 0, 0, 0);
      }
      // C/D layout: col = lane&15, row = (lane>>4)*4 + reg (m89-verified)
      const int r0 = (lane >> 4) * 4;
#pragma unroll
      for (int r = 0; r < 4; ++r)
        red[w * 272 + (r0 + r) * 17 + m] = acc[r];
    }
    __syncthreads();

    // --- reduce 8 wave partials ---
    if (act && tid < 256) {
      const int b = tid >> 4, c = tid & 15;
      float s = 0.f;
#pragma unroll
      for (int ww = 0; ww < 8; ++ww) s += red[ww * 272 + b * 17 + c];
      gates[tid] = s;
    }
    __syncthreads();

    // --- activations + packed h publish ---
    if (act && tid < 64) {
      const int b = tid >> 2, j = tid & 3;
      const float gi = gates[b * 16 + j] + bb0;
      const float gf = gates[b * 16 + 4 + j] + bb1;
      const float gg = gates[b * 16 + 8 + j] + bb2;
      const float go = gates[b * 16 + 12 + j] + bb3;
      const float si = 1.f / (1.f + __expf(-gi));
      const float sf = 1.f / (1.f + __expf(-gf));
      const float e2g = __expf(2.f * gg);
      const float tg = 1.f - 2.f / (e2g + 1.f);
      const float so = 1.f / (1.f + __expf(-go));
      const float cn = sf * c_state + si * tg;
      c_state = cn;
      const float e2c = __expf(2.f * cn);
      const float hn = so * (1.f - 2.f / (e2c + 1.f));
      const unsigned short hh = f2bf(hn);
      const unsigned short hl = f2bf(hn - bf2f(hh));
      const unsigned pk = ((unsigned)hh << 16) | (unsigned)hl;
      unsigned* hdst = (layer == 0)
          ? hex1 + (ph & 1) * 8192 + b * 512 + (u0 + j)
          : hex2 + ((ph - 1) & 1) * 8192 + b * 512 + (u0 + j);
      flagst(hdst, pk);  // sc1 -> coherence point
      if (layer == 1) {
        const size_t r = (size_t)(ph - 1) * 16 + b;
        Ah[r * Hn + u0 + j] = hh;
        Al[r * Hn + u0 + j] = hl;
      }
    }
    __syncthreads();  // drains publish stores (compiler vmcnt(0) before s_barrier)

    if (tid == 0) flagst(bar_my, target);

    // --- overlap the wait: L0 pre-stages embed x for the next step ---
    if (layer == 0 && (ph + 1) < Tn) {
      const int t1 = ph + 1;
      const int tokA = tokens[rowA * Tn + t1];
      const int tokB = tokens[rowB * Tn + t1];
      const float* sA = embed + (size_t)tokA * Hn + slotA * 8;
      const float* sB = embed + (size_t)tokB * Hn + slotB * 8;
      cvt8(*(const f32x4*)sA, *(const f32x4*)(sA + 4), &Xh[offA], &Xl[offA]);
      cvt8(*(const f32x4*)sB, *(const f32x4*)(sB + 4), &Xh[offB], &Xl[offB]);
    }

    // --- flat certify barrier ---
    if (tid < 256) {
      while (pollld(bar_poll) < target) __builtin_amdgcn_s_sleep(2);
    }
    __syncthreads();
  }
}

// ---------------- projection GEMM: out[b][t][v] = H2 @ Wout + bout ----------
// XCD-banded grid (round-11 verified win): each XCD owns an 8-m-tile A band
// (2.1 MB, L2-resident); 8 consecutive blocks share one B panel (262 KB).
__global__ __launch_bounds__(256) void proj_gemm(
    const unsigned short* __restrict__ Ah_, const unsigned short* __restrict__ Al_,
    const unsigned short* __restrict__ Bh_, const unsigned short* __restrict__ Bl_,
    const float* __restrict__ bout, float* __restrict__ out) {
  __shared__ unsigned short sAh[128 * PSTR], sAl[128 * PSTR], sBh[128 * PSTR], sBl[128 * PSTR];
  const int tid = threadIdx.x;
  const int id = blockIdx.x;
  // bijective remap: xcd = id&7 gets m-tiles [8*xcd, 8*xcd+8), n sweeps slowest
  const int mt = (id & 7) * 8 + ((id >> 3) & 7);   // 0..63
  const int m0 = mt * 128;
  const int n0 = (id >> 6) * 128;                  // 0..249 tiles
  const int lane = tid & 63, w = tid >> 6;
  const int wm = (w & 1) * 64, wn = (w >> 1) * 64;

  f32x4 acc[4][4];
#pragma unroll
  for (int i = 0; i < 4; ++i)
#pragma unroll
    for (int j = 0; j < 4; ++j) acc[i][j] = (f32x4){0.f, 0.f, 0.f, 0.f};

  for (int kt = 0; kt < 16; ++kt) {
    const int k0 = kt * 32;
    __syncthreads();
#pragma unroll
    for (int i = 0; i < 8; ++i) {
      const int chunk = ((i & 1) << 8) + tid;
      const int mrow = chunk >> 2;
      const int kc = chunk & 3;
      const int tsel = i >> 1;
      const unsigned short* gsrc =
          (tsel == 0) ? Ah_ + (size_t)(m0 + mrow) * Hn + k0 + kc * 8 :
          (tsel == 1) ? Al_ + (size_t)(m0 + mrow) * Hn + k0 + kc * 8 :
          (tsel == 2) ? Bh_ + (size_t)(n0 + mrow) * Hn + k0 + kc * 8 :
                        Bl_ + (size_t)(n0 + mrow) * Hn + k0 + kc * 8;
      unsigned short* ldst = (tsel == 0) ? sAh : (tsel == 1) ? sAl : (tsel == 2) ? sBh : sBl;
      *(i32x4*)&ldst[mrow * PSTR + kc * 8] = *(const i32x4*)gsrc;
    }
    __syncthreads();

    short8 fah[4], fal[4], fbh[4], fbl[4];
    const int rlo = lane & 15, kg = (lane >> 4) * 8;
#pragma unroll
    for (int f = 0; f < 4; ++f) {
      fah[f] = *(const short8*)&sAh[(wm + f * 16 + rlo) * PSTR + kg];
      fal[f] = *(const short8*)&sAl[(wm + f * 16 + rlo) * PSTR + kg];
      fbh[f] = *(const short8*)&sBh[(wn + f * 16 + rlo) * PSTR + kg];
      fbl[f] = *(const short8*)&sBl[(wn + f * 16 + rlo) * PSTR + kg];
    }
#pragma unroll
    for (int i = 0; i < 4; ++i)
#pragma unroll
      for (int j = 0; j < 4; ++j) {
        acc[i][j] = __builtin_amdgcn_mfma_f32_16x16x32_bf16(fah[i], fbh[j], acc[i][j], 0, 0, 0);
        acc[i][j] = __builtin_amdgcn_mfma_f32_16x16x32_bf16(fah[i], fbl[j], acc[i][j], 0, 0, 0);
        acc[i][j] = __builtin_amdgcn_mfma_f32_16x16x32_bf16(fal[i], fbh[j], acc[i][j], 0, 0, 0);
      }
  }

#pragma unroll
  for (int j = 0; j < 4; ++j) {
    const int n = n0 + wn + j * 16 + (lane & 15);
    const float bv = bout[n];
#pragma unroll
    for (int i = 0; i < 4; ++i) {
#pragma unroll
      for (int r = 0; r < 4; ++r) {
        const int m = m0 + wm + i * 16 + ((lane >> 4) * 4) + r;
        out[(size_t)(m & 15) * ((size_t)Tn * Vn) + (size_t)(m >> 4) * Vn + n] =
            acc[i][j][r] + bv;
      }
    }
  }
}

extern "C" void kernel_launch(void* const* d_in, const int* in_sizes, int n_in,
                              void* d_out, int out_size, void* d_ws, size_t ws_size,
                              hipStream_t stream) {
  const int*   tokens = (const int*)d_in[0];
  const float* embed  = (const float*)d_in[1];
  const float* W      = (const float*)d_in[2];
  const float* bias   = (const float*)d_in[3];
  const float* Wout   = (const float*)d_in[4];
  const float* bout   = (const float*)d_in[5];
  float* out = (float*)d_out;

  char* ws = (char*)d_ws;
  unsigned* arr  = (unsigned*)ws;                      // 256 * 2048 B barrier slots
  unsigned* hex1 = (unsigned*)(ws + 524288);           // 2 slots * 16*512 u32
  unsigned* hex2 = (unsigned*)(ws + 524288 + 65536);   // 2 slots * 16*512 u32
  unsigned short* Ah  = (unsigned short*)(ws + 655360);
  unsigned short* Al  = Ah + (size_t)8192 * 512;
  unsigned short* BhT = Al + (size_t)8192 * 512;
  unsigned short* BlT = BhT + (size_t)32000 * 512;
  // total ws use: ~83 MB

  // zero barrier slots + packed h exchange buffers (fresh every launch;
  // zeroed hex slots double as h[-1] = 0 for the first phases)
  hipMemsetAsync(d_ws, 0, 655360, stream);

  wout_convert<<<dim3(500, 8), 256, 0, stream>>>(Wout, BhT, BlT);

  const size_t ldsbytes = (size_t)(4 * 16 * XSTR) * 2 +
                          (size_t)(8 * 272 + 256) * 4;  // 141824
  (void)hipFuncSetAttribute((const void*)lstm_scan,
                            hipFuncAttributeMaxDynamicSharedMemorySize, (int)ldsbytes);
  lstm_scan<<<NBLK, 512, ldsbytes, stream>>>(tokens, embed, W, bias,
                                             hex1, hex2, Ah, Al, arr);

  proj_gemm<<<16000, 256, 0, stream>>>(Ah, Al, BhT, BlT, bout, out);
}